// Round 1
// baseline (1459.362 us; speedup 1.0000x reference)
//
#include <hip/hip_runtime.h>
#include <math.h>

#define BDIM 256
constexpr int BB = 4, C = 128, Hh = 128, Wd = 128, HW = Hh * Wd, K2n = 9;
constexpr float EPSv = 1e-5f;

__device__ __forceinline__ float sigmoidf_(float v) { return 1.f / (1.f + expf(-v)); }

// ---- weight repack: w[co][ci][k] -> wr[(ci*9+k)*coutPad + co], zero-pad co ----
__global__ void repack_w_k(const float* __restrict__ w, float* __restrict__ wr,
                           int cout, int coutPad) {
    int idx = blockIdx.x * BDIM + threadIdx.x;
    int total = C * 9 * coutPad;
    if (idx >= total) return;
    int co = idx % coutPad;
    int cik = idx / coutPad;
    int ci = cik / 9, kk = cik % 9;
    wr[idx] = (co < cout) ? w[((size_t)co * C + ci) * 9 + kk] : 0.f;
}

// off(18) + mask(9) packed into 32 padded couts; bias packed too
__global__ void repack_offmask_k(const float* __restrict__ w_off, const float* __restrict__ w_mask,
                                 const float* __restrict__ b_off, const float* __restrict__ b_mask,
                                 float* __restrict__ wr, float* __restrict__ br) {
    int idx = blockIdx.x * BDIM + threadIdx.x;
    int total = C * 9 * 32;
    if (idx >= total) return;
    int co = idx & 31;
    int cik = idx >> 5;
    int ci = cik / 9, kk = cik % 9;
    float v = 0.f;
    if (co < 18)      v = w_off[((size_t)co * C + ci) * 9 + kk];
    else if (co < 27) v = w_mask[((size_t)(co - 18) * C + ci) * 9 + kk];
    wr[idx] = v;
    if (idx < 32) br[idx] = (idx < 18) ? b_off[idx] : (idx < 27 ? b_mask[idx - 18] : 0.f);
}

// ---- direct conv3x3, pad=1. Block: 1 row x 32 couts. Thread: 2 px x 8 couts. ----
// EPI: 0 = none, 1 = sigmoid
template <int EPI>
__global__ __launch_bounds__(256) void conv3x3_k(
    const float* __restrict__ x, const float* __restrict__ wr,
    const float* __restrict__ bias, float* __restrict__ out, int coutPad) {
    constexpr int CICH = 8;
    const int h = blockIdx.x, cblk = blockIdx.y, b = blockIdx.z;
    const int t = threadIdx.x;
    const int w0 = (t & 63) * 2;
    const int cog = t >> 6;  // wave-uniform
    const int co0 = __builtin_amdgcn_readfirstlane(cblk * 32 + cog * 8);

    __shared__ float xs[CICH][3][Wd + 2];
    float acc[16];
#pragma unroll
    for (int i = 0; i < 16; i++) acc[i] = 0.f;

    const float* xb = x + (size_t)b * C * HW;
    for (int c0 = 0; c0 < C; c0 += CICH) {
        __syncthreads();
        for (int i = t; i < CICH * 3 * (Wd + 2); i += BDIM) {
            int col = i % (Wd + 2);
            int rr = (i / (Wd + 2)) % 3;
            int cc = i / (3 * (Wd + 2));
            int hh = h + rr - 1, ww = col - 1;
            float v = 0.f;
            if ((unsigned)hh < (unsigned)Hh && (unsigned)ww < (unsigned)Wd)
                v = xb[(size_t)(c0 + cc) * HW + hh * Wd + ww];
            xs[cc][rr][col] = v;
        }
        __syncthreads();
#pragma unroll
        for (int cc = 0; cc < CICH; cc++) {
            float xv[3][4];
#pragma unroll
            for (int r = 0; r < 3; r++)
#pragma unroll
                for (int q = 0; q < 4; q++) xv[r][q] = xs[cc][r][w0 + q];
            const float* wp = wr + (size_t)(c0 + cc) * 9 * coutPad + co0;
#pragma unroll
            for (int k = 0; k < 9; k++) {
                const int r = k / 3, q = k % 3;
                const float a0 = xv[r][q], a1 = xv[r][q + 1];
                const float4 wa = *(const float4*)(wp + k * coutPad);
                const float4 wb = *(const float4*)(wp + k * coutPad + 4);
                acc[0]  += a0 * wa.x; acc[1]  += a1 * wa.x;
                acc[2]  += a0 * wa.y; acc[3]  += a1 * wa.y;
                acc[4]  += a0 * wa.z; acc[5]  += a1 * wa.z;
                acc[6]  += a0 * wa.w; acc[7]  += a1 * wa.w;
                acc[8]  += a0 * wb.x; acc[9]  += a1 * wb.x;
                acc[10] += a0 * wb.y; acc[11] += a1 * wb.y;
                acc[12] += a0 * wb.z; acc[13] += a1 * wb.z;
                acc[14] += a0 * wb.w; acc[15] += a1 * wb.w;
            }
        }
    }
    const int pix = h * Wd + w0;
#pragma unroll
    for (int j = 0; j < 8; j++) {
        int co = co0 + j;
        float bv = bias[co];
        float v0 = acc[j * 2] + bv, v1 = acc[j * 2 + 1] + bv;
        if (EPI == 1) { v0 = sigmoidf_(v0); v1 = sigmoidf_(v1); }
        *(float2*)(out + (size_t)(b * coutPad + co) * HW + pix) = make_float2(v0, v1);
    }
}

// ---- instance-norm stats: one block per (b,c) ----
__global__ __launch_bounds__(256) void inorm_stats_k(const float* __restrict__ src,
                                                     float* __restrict__ mu,
                                                     float* __restrict__ rsig) {
    const int bc = blockIdx.x;
    const float* p = src + (size_t)bc * HW;
    float s = 0.f, s2 = 0.f;
    for (int i = threadIdx.x; i < HW; i += BDIM) {
        float v = p[i];
        s += v; s2 += v * v;
    }
    __shared__ float ss[BDIM], sq[BDIM];
    int t = threadIdx.x;
    ss[t] = s; sq[t] = s2;
    __syncthreads();
    for (int off = BDIM / 2; off > 0; off >>= 1) {
        if (t < off) { ss[t] += ss[t + off]; sq[t] += sq[t + off]; }
        __syncthreads();
    }
    if (t == 0) {
        float m = ss[0] / HW;
        float var = sq[0] / HW - m * m;
        mu[bc] = m;
        rsig[bc] = rsqrtf(var + EPSv);
    }
}

// ---- x_attned = lrelu(norm(feat)) * attn ----
__global__ void xattned_k(const float* __restrict__ feat, const float* __restrict__ attn,
                          const float* __restrict__ mu, const float* __restrict__ rsig,
                          float* __restrict__ xa) {
    size_t i = (size_t)blockIdx.x * BDIM + threadIdx.x;
    if (i >= (size_t)BB * C * HW) return;
    int bc = (int)(i / HW);
    float v = (feat[i] - mu[bc]) * rsig[bc];
    v = v > 0.f ? v : 0.2f * v;
    xa[i] = v * attn[i];
}

// ---- deformable conv: gather + 128x(128*9) contraction ----
__global__ __launch_bounds__(256) void deform_k(
    const float* __restrict__ xa, const float* __restrict__ om,
    const float* __restrict__ wr, const float* __restrict__ b_org,
    float* __restrict__ dconv) {
    constexpr int CCH = 4;
    const int b = blockIdx.z, h = blockIdx.y, wseg = blockIdx.x;
    const int t = threadIdx.x;
    const int p = t & 63;
    const int g = __builtin_amdgcn_readfirstlane(t >> 6);

    __shared__ int   a4[64][K2n][4];
    __shared__ float w4[64][K2n][4];
    __shared__ float sv[CCH][64][K2n];

    const float* omb = om + (size_t)b * 32 * HW;
    for (int task = t; task < 64 * K2n; task += BDIM) {
        int pp = task / K2n, k = task % K2n;
        int ww = wseg * 64 + pp;
        int pix = h * Wd + ww;
        float dy = omb[(size_t)(2 * k) * HW + pix];
        float dx = omb[(size_t)(2 * k + 1) * HW + pix];
        float m = sigmoidf_(omb[(size_t)(18 + k) * HW + pix]);
        float yy = dy + (float)(h + k / 3 - 1);
        float xx = dx + (float)(ww + k % 3 - 1);
        float y0f = floorf(yy), x0f = floorf(xx);
        float wy = yy - y0f, wx = xx - x0f;
        int y0 = (int)y0f, x0 = (int)x0f;
#pragma unroll
        for (int c2 = 0; c2 < 4; c2++) {
            int ddy = c2 >> 1, ddx = c2 & 1;
            int yi = y0 + ddy, xi = x0 + ddx;
            bool valid = (yi >= 0) && (yi < Hh) && (xi >= 0) && (xi < Wd);
            int yc = min(max(yi, 0), Hh - 1), xc = min(max(xi, 0), Wd - 1);
            float wt = (ddy ? wy : 1.f - wy) * (ddx ? wx : 1.f - wx);
            a4[pp][k][c2] = yc * Wd + xc;
            w4[pp][k][c2] = valid ? wt * m : 0.f;
        }
    }
    __syncthreads();

    float acc[32];
#pragma unroll
    for (int i = 0; i < 32; i++) acc[i] = 0.f;
    const float* xab = xa + (size_t)b * C * HW;

    for (int c0 = 0; c0 < C; c0 += CCH) {
        __syncthreads();
        for (int task = t; task < CCH * 64 * K2n; task += BDIM) {
            int k = task % K2n;
            int pp = (task / K2n) & 63;
            int cc = task / (K2n * 64);
            const float* base = xab + (size_t)(c0 + cc) * HW;
            sv[cc][pp][k] = w4[pp][k][0] * base[a4[pp][k][0]]
                          + w4[pp][k][1] * base[a4[pp][k][1]]
                          + w4[pp][k][2] * base[a4[pp][k][2]]
                          + w4[pp][k][3] * base[a4[pp][k][3]];
        }
        __syncthreads();
#pragma unroll
        for (int cc = 0; cc < CCH; cc++) {
            const float* wp = wr + (size_t)(c0 + cc) * 9 * C + g * 32;
#pragma unroll
            for (int k = 0; k < K2n; k++) {
                float s = sv[cc][p][k];
                const float4* wv = (const float4*)(wp + k * C);
#pragma unroll
                for (int q = 0; q < 8; q++) {
                    float4 wq = wv[q];
                    acc[q * 4 + 0] += s * wq.x;
                    acc[q * 4 + 1] += s * wq.y;
                    acc[q * 4 + 2] += s * wq.z;
                    acc[q * 4 + 3] += s * wq.w;
                }
            }
        }
    }
    const int pix = h * Wd + wseg * 64 + p;
#pragma unroll
    for (int j = 0; j < 32; j++) {
        int co = g * 32 + j;
        dconv[(size_t)(b * C + co) * HW + pix] = acc[j] + b_org[co];
    }
}

// ---- out = x_attned + lrelu(norm(dconv)) * (1 - attn) ----
__global__ void final_k(const float* __restrict__ xa, const float* __restrict__ attn,
                        const float* __restrict__ dconv, const float* __restrict__ mu,
                        const float* __restrict__ rsig, float* __restrict__ out) {
    size_t i = (size_t)blockIdx.x * BDIM + threadIdx.x;
    if (i >= (size_t)BB * C * HW) return;
    int bc = (int)(i / HW);
    float v = (dconv[i] - mu[bc]) * rsig[bc];
    v = v > 0.f ? v : 0.2f * v;
    float a = attn[i];
    out[i] = xa[i] + v * (1.f - a);
}

extern "C" void kernel_launch(void* const* d_in, const int* in_sizes, int n_in,
                              void* d_out, int out_size, void* d_ws, size_t ws_size,
                              hipStream_t stream) {
    const float* x      = (const float*)d_in[0];
    const float* w_attn = (const float*)d_in[1];
    const float* b_attn = (const float*)d_in[2];
    const float* w_feat = (const float*)d_in[3];
    const float* b_feat = (const float*)d_in[4];
    const float* w_org  = (const float*)d_in[5];
    const float* b_org  = (const float*)d_in[6];
    const float* w_off  = (const float*)d_in[7];
    const float* b_off  = (const float*)d_in[8];
    const float* w_mask = (const float*)d_in[9];
    const float* b_mask = (const float*)d_in[10];
    float* out = (float*)d_out;

    float* ws = (float*)d_ws;
    size_t o = 0;
    float* attn  = ws + o; o += (size_t)BB * C * HW;   // attn (post-sigmoid)
    float* featd = ws + o; o += (size_t)BB * C * HW;   // feat_raw, later reused as dconv
    float* xa    = ws + o; o += (size_t)BB * C * HW;   // x_attned
    float* offm  = ws + o; o += (size_t)BB * 32 * HW;  // off(18)+mask(9) raw, padded 32ch
    float* wrA   = ws + o; o += (size_t)C * 9 * C;
    float* wrF   = ws + o; o += (size_t)C * 9 * C;
    float* wrO   = ws + o; o += (size_t)C * 9 * C;
    float* wrOM  = ws + o; o += (size_t)C * 9 * 32;
    float* bOM   = ws + o; o += 32;
    float* mu1   = ws + o; o += 512;
    float* rs1   = ws + o; o += 512;
    float* mu2   = ws + o; o += 512;
    float* rs2   = ws + o; o += 512;
    (void)ws_size; (void)in_sizes; (void)n_in; (void)out_size;

    const int rpBlocks = (C * 9 * C + BDIM - 1) / BDIM;
    repack_w_k<<<rpBlocks, BDIM, 0, stream>>>(w_attn, wrA, C, C);
    repack_w_k<<<rpBlocks, BDIM, 0, stream>>>(w_feat, wrF, C, C);
    repack_w_k<<<rpBlocks, BDIM, 0, stream>>>(w_org,  wrO, C, C);
    repack_offmask_k<<<(C * 9 * 32 + BDIM - 1) / BDIM, BDIM, 0, stream>>>(
        w_off, w_mask, b_off, b_mask, wrOM, bOM);

    conv3x3_k<1><<<dim3(Hh, C / 32, BB), BDIM, 0, stream>>>(x, wrA, b_attn, attn, C);
    conv3x3_k<0><<<dim3(Hh, C / 32, BB), BDIM, 0, stream>>>(x, wrF, b_feat, featd, C);
    inorm_stats_k<<<BB * C, BDIM, 0, stream>>>(featd, mu1, rs1);

    const int nElem = BB * C * HW;
    xattned_k<<<(nElem + BDIM - 1) / BDIM, BDIM, 0, stream>>>(featd, attn, mu1, rs1, xa);

    conv3x3_k<0><<<dim3(Hh, 1, BB), BDIM, 0, stream>>>(xa, wrOM, bOM, offm, 32);
    deform_k<<<dim3(2, Hh, BB), BDIM, 0, stream>>>(xa, offm, wrO, b_org, featd);
    inorm_stats_k<<<BB * C, BDIM, 0, stream>>>(featd, mu2, rs2);
    final_k<<<(nElem + BDIM - 1) / BDIM, BDIM, 0, stream>>>(xa, attn, featd, mu2, rs2, out);
}

// Round 2
// 354.301 us; speedup vs baseline: 4.1190x; 4.1190x over previous
//
#include <hip/hip_runtime.h>
#include <math.h>

#define BDIM 256
constexpr int BB = 4, Cc = 128, Hh = 128, Wd = 128, HW = Hh * Wd;
constexpr float EPSv = 1e-5f;

typedef __attribute__((ext_vector_type(8))) short short8v;
typedef __attribute__((ext_vector_type(4))) float floatx4;

#define MFMA16(a, b, c) __builtin_amdgcn_mfma_f32_16x16x32_bf16((a), (b), (c), 0, 0, 0)

__device__ __forceinline__ float sigmoidf_(float v) { return 1.f / (1.f + __expf(-v)); }

__device__ __forceinline__ unsigned short f2bf(float f) {
    union { float f; unsigned u; } v; v.f = f;
    unsigned r = v.u + 0x7FFFu + ((v.u >> 16) & 1u);
    return (unsigned short)(r >> 16);
}

// ---- weight repack into per-lane MFMA fragment order ----
// dst[cot][chunk][tap][lane][i] = w[co=cot*16+(lane&15)][ci=chunk*32+(lane>>4)*8+i][tap]
__global__ void repack_conv_k(const float* __restrict__ w, unsigned short* __restrict__ dst,
                              int ncot, int cout) {
    int idx = blockIdx.x * BDIM + threadIdx.x;
    int total = ncot * 4 * 9 * 64 * 8;
    if (idx >= total) return;
    int i = idx & 7;
    int lane = (idx >> 3) & 63;
    int tap = (idx >> 9) % 9;
    int chunk = (idx / (9 * 512)) & 3;
    int cot = idx / (4 * 9 * 512);
    int co = cot * 16 + (lane & 15);
    int ci = chunk * 32 + (lane >> 4) * 8 + i;
    float v = (co < cout) ? w[((size_t)co * Cc + ci) * 9 + tap] : 0.f;
    dst[idx] = f2bf(v);
}

// off(18)+mask(9) merged, padded to 32 couts (2 cotiles)
__global__ void repack_om_k(const float* __restrict__ w_off, const float* __restrict__ w_mask,
                            unsigned short* __restrict__ dst) {
    int idx = blockIdx.x * BDIM + threadIdx.x;
    int total = 2 * 4 * 9 * 64 * 8;
    if (idx >= total) return;
    int i = idx & 7;
    int lane = (idx >> 3) & 63;
    int tap = (idx >> 9) % 9;
    int chunk = (idx / (9 * 512)) & 3;
    int cot = idx / (4 * 9 * 512);
    int co = cot * 16 + (lane & 15);
    int ci = chunk * 32 + (lane >> 4) * 8 + i;
    float v = 0.f;
    if (co < 18)      v = w_off[((size_t)co * Cc + ci) * 9 + tap];
    else if (co < 27) v = w_mask[((size_t)(co - 18) * Cc + ci) * 9 + tap];
    dst[idx] = f2bf(v);
}

__global__ void pack_bom_k(const float* __restrict__ b_off, const float* __restrict__ b_mask,
                           float* __restrict__ bom) {
    int i = threadIdx.x;
    if (i < 32) bom[i] = (i < 18) ? b_off[i] : (i < 27 ? b_mask[i - 18] : 0.f);
}

// ---- MFMA implicit-GEMM conv3x3 (pad=1). Block: COTPB*16 couts x 128 px (one row). ----
// 4 waves: WCO x (4/WCO). sigmoid applied when block's couts < sigsplit (block-uniform).
template <int COTPB, int WCO>
__global__ __launch_bounds__(256) void convmf_k(
    const float* __restrict__ x, const unsigned short* __restrict__ wpk,
    const float* __restrict__ biasA, const float* __restrict__ biasB,
    int bsplit, int sigsplit,
    float* __restrict__ out, int ldc, int ch0) {
    constexpr int WPX = 4 / WCO;
    constexpr int PS = 8 / WPX;  // px-subtiles per wave
    const int cb = blockIdx.x, h = blockIdx.y, b = blockIdx.z;
    const int t = threadIdx.x;
    const int lane = t & 63, llo = t & 15, lhi = (t >> 4) & 3;
    const int wid = t >> 6;
    const int wr = wid / WPX, wc = wid % WPX;

    __shared__ unsigned short xs[3][4][132][8];

    floatx4 acc[2][PS];
#pragma unroll
    for (int c = 0; c < 2; c++)
#pragma unroll
        for (int ps = 0; ps < PS; ps++) acc[c][ps] = (floatx4){0.f, 0.f, 0.f, 0.f};

    const float* xb = x + (size_t)b * Cc * HW;

    for (int chunk = 0; chunk < 4; ++chunk) {
        __syncthreads();
        for (int task = t; task < 3120; task += BDIM) {
            int j = task % 130;
            int rc = task / 130;
            int r = rc >> 3, ci4 = rc & 7;
            int hh = h + r - 1, col = j - 1;
            float v0 = 0.f, v1 = 0.f, v2 = 0.f, v3 = 0.f;
            if ((unsigned)hh < (unsigned)Hh && (unsigned)col < (unsigned)Wd) {
                const float* p = xb + (size_t)(chunk * 32 + ci4 * 4) * HW + hh * Wd + col;
                v0 = p[0]; v1 = p[HW]; v2 = p[2 * HW]; v3 = p[3 * HW];
            }
            ushort4 u;
            u.x = f2bf(v0); u.y = f2bf(v1); u.z = f2bf(v2); u.w = f2bf(v3);
            *(ushort4*)&xs[r][ci4 >> 1][j][(ci4 & 1) * 4] = u;
        }
        __syncthreads();
#pragma unroll
        for (int tap = 0; tap < 9; ++tap) {
            const int r = tap / 3, dx = tap % 3;
            short8v af[2];
#pragma unroll
            for (int c = 0; c < 2; c++) {
                int cot = cb * COTPB + wr * 2 + c;
                af[c] = *(const short8v*)(wpk + ((((size_t)cot * 4 + chunk) * 9 + tap) * 64 + lane) * 8);
            }
            short8v bf[PS];
#pragma unroll
            for (int ps = 0; ps < PS; ps++)
                bf[ps] = *(const short8v*)&xs[r][lhi][wc * (PS * 16) + ps * 16 + llo + dx][0];
#pragma unroll
            for (int c = 0; c < 2; c++)
#pragma unroll
                for (int ps = 0; ps < PS; ps++)
                    acc[c][ps] = MFMA16(af[c], bf[ps], acc[c][ps]);
        }
    }

    const int cbase = cb * (COTPB * 16);
    const float* bp = (cbase < bsplit) ? biasA : biasB;
    const int bshift = (cbase < bsplit) ? 0 : bsplit;
    const bool dosig = cbase < sigsplit;
#pragma unroll
    for (int c = 0; c < 2; c++)
#pragma unroll
        for (int ps = 0; ps < PS; ps++)
#pragma unroll
            for (int reg = 0; reg < 4; reg++) {
                int co = cbase + (wr * 2 + c) * 16 + lhi * 4 + reg;
                int px = wc * (PS * 16) + ps * 16 + llo;
                float v = acc[c][ps][reg] + bp[co - bshift];
                if (dosig) v = sigmoidf_(v);
                out[((size_t)b * ldc + ch0 + co) * HW + h * Wd + px] = v;
            }
}

// ---- instance-norm stats over rawAF-style buffer ----
__global__ __launch_bounds__(256) void inorm_stats_k(const float* __restrict__ src,
                                                     float* __restrict__ mu, float* __restrict__ rsig,
                                                     int chTot, int ch0) {
    const int bc = blockIdx.x;
    const int b = bc >> 7, c = bc & 127;
    const float4* p = (const float4*)(src + ((size_t)b * chTot + ch0 + c) * HW);
    float s = 0.f, s2 = 0.f;
    for (int i = threadIdx.x; i < HW / 4; i += BDIM) {
        float4 v = p[i];
        s += v.x + v.y + v.z + v.w;
        s2 += v.x * v.x + v.y * v.y + v.z * v.z + v.w * v.w;
    }
    __shared__ float ss[BDIM], sq[BDIM];
    int t = threadIdx.x;
    ss[t] = s; sq[t] = s2;
    __syncthreads();
    for (int off = BDIM / 2; off > 0; off >>= 1) {
        if (t < off) { ss[t] += ss[t + off]; sq[t] += sq[t + off]; }
        __syncthreads();
    }
    if (t == 0) {
        float m = ss[0] / HW;
        float var = sq[0] / HW - m * m;
        mu[bc] = m;
        rsig[bc] = rsqrtf(var + EPSv);
    }
}

// ---- xa = lrelu(norm(featRaw)) * attn ----
__global__ void xattned_k(const float* __restrict__ rawAF, const float* __restrict__ mu,
                          const float* __restrict__ rsig, float* __restrict__ xa) {
    size_t i4 = (size_t)blockIdx.x * BDIM + threadIdx.x;
    const size_t n4 = (size_t)BB * Cc * HW / 4;
    if (i4 >= n4) return;
    int plane = (int)(i4 / (HW / 4));
    int w4 = (int)(i4 % (HW / 4));
    int b = plane >> 7, c = plane & 127;
    const float4 a = *(const float4*)(rawAF + ((size_t)b * 256 + c) * HW + w4 * 4);
    float4 f = *(const float4*)(rawAF + ((size_t)b * 256 + 128 + c) * HW + w4 * 4);
    float m = mu[plane], rs = rsig[plane];
    float4 o;
    float v;
    v = (f.x - m) * rs; v = v > 0.f ? v : 0.2f * v; o.x = v * a.x;
    v = (f.y - m) * rs; v = v > 0.f ? v : 0.2f * v; o.y = v * a.y;
    v = (f.z - m) * rs; v = v > 0.f ? v : 0.2f * v; o.z = v * a.z;
    v = (f.w - m) * rs; v = v > 0.f ? v : 0.2f * v; o.w = v * a.w;
    *(float4*)(xa + (size_t)plane * HW + w4 * 4) = o;
}

// ---- deformable conv: register-table gather -> bf16 im2col LDS -> MFMA ----
__global__ __launch_bounds__(256) void deform_mfma_k(
    const float* __restrict__ xa, const float* __restrict__ om,
    const unsigned short* __restrict__ wpkO, const float* __restrict__ b_org,
    float* __restrict__ out, int ldc, int ch0) {
    const int seg = blockIdx.x, h = blockIdx.y, b = blockIdx.z;
    const int t = threadIdx.x;
    const int lane = t & 63, llo = t & 15, lhi = (t >> 4) & 3;
    const int wid = t >> 6;

    __shared__ unsigned short sv[4][9][64][8];  // [cigrp][tap][px][ci8]

    // per-thread gather tables (registers; all loops fully unrolled)
    int prA[3][4];
    float prW[3][4];
    int prOff[3];
    bool prV[3];

    const float* omb = om + (size_t)b * 32 * HW;
#pragma unroll
    for (int u = 0; u < 3; u++) {
        int p = t + u * 256;
        bool valid = p < 576;
        int pc = valid ? p : 0;
        int tap = pc >> 6, pxl = pc & 63;
        int ww = seg * 64 + pxl;
        int pix = h * Wd + ww;
        float dy = omb[(size_t)(2 * tap) * HW + pix];
        float dxv = omb[(size_t)(2 * tap + 1) * HW + pix];
        float msk = sigmoidf_(omb[(size_t)(18 + tap) * HW + pix]);
        float yy = dy + (float)(h + tap / 3 - 1);
        float xx = dxv + (float)(ww + tap % 3 - 1);
        float y0f = floorf(yy), x0f = floorf(xx);
        float wy = yy - y0f, wx = xx - x0f;
        int y0 = (int)y0f, x0 = (int)x0f;
#pragma unroll
        for (int c2 = 0; c2 < 4; c2++) {
            int ddy = c2 >> 1, ddx = c2 & 1;
            int yi = y0 + ddy, xi = x0 + ddx;
            bool vc = (yi >= 0) && (yi < Hh) && (xi >= 0) && (xi < Wd);
            int yc = min(max(yi, 0), Hh - 1), xc = min(max(xi, 0), Wd - 1);
            float wt = (ddy ? wy : 1.f - wy) * (ddx ? wx : 1.f - wx);
            prA[u][c2] = yc * Wd + xc;
            prW[u][c2] = vc ? wt * msk : 0.f;
        }
        prOff[u] = tap * 64 + pxl;
        prV[u] = valid;
    }

    floatx4 acc[2][4];
#pragma unroll
    for (int c = 0; c < 2; c++)
#pragma unroll
        for (int ps = 0; ps < 4; ps++) acc[c][ps] = (floatx4){0.f, 0.f, 0.f, 0.f};

    const float* xab = xa + (size_t)b * Cc * HW;
    unsigned short* svf = &sv[0][0][0][0];

    for (int chunk = 0; chunk < 4; ++chunk) {
        __syncthreads();
#pragma unroll
        for (int u = 0; u < 3; u++) {
            if (prV[u]) {
#pragma unroll
                for (int cg = 0; cg < 4; cg++) {
                    const float* pb = xab + (size_t)(chunk * 32 + cg * 8) * HW;
                    unsigned q[4];
#pragma unroll
                    for (int pair = 0; pair < 4; pair++) {
                        const float* p0 = pb + (size_t)(2 * pair) * HW;
                        const float* p1 = pb + (size_t)(2 * pair + 1) * HW;
                        float va = prW[u][0] * p0[prA[u][0]] + prW[u][1] * p0[prA[u][1]]
                                 + prW[u][2] * p0[prA[u][2]] + prW[u][3] * p0[prA[u][3]];
                        float vb = prW[u][0] * p1[prA[u][0]] + prW[u][1] * p1[prA[u][1]]
                                 + prW[u][2] * p1[prA[u][2]] + prW[u][3] * p1[prA[u][3]];
                        q[pair] = (unsigned)f2bf(va) | ((unsigned)f2bf(vb) << 16);
                    }
                    uint4 pk = make_uint4(q[0], q[1], q[2], q[3]);
                    *(uint4*)(svf + ((size_t)(cg * 576 + prOff[u]) << 3)) = pk;
                }
            }
        }
        __syncthreads();
#pragma unroll
        for (int tap = 0; tap < 9; ++tap) {
            short8v af[2];
#pragma unroll
            for (int c = 0; c < 2; c++) {
                int cot = wid * 2 + c;
                af[c] = *(const short8v*)(wpkO + ((((size_t)cot * 4 + chunk) * 9 + tap) * 64 + lane) * 8);
            }
            short8v bf[4];
#pragma unroll
            for (int ps = 0; ps < 4; ps++)
                bf[ps] = *(const short8v*)&sv[lhi][tap][ps * 16 + llo][0];
#pragma unroll
            for (int c = 0; c < 2; c++)
#pragma unroll
                for (int ps = 0; ps < 4; ps++)
                    acc[c][ps] = MFMA16(af[c], bf[ps], acc[c][ps]);
        }
    }

#pragma unroll
    for (int c = 0; c < 2; c++)
#pragma unroll
        for (int ps = 0; ps < 4; ps++)
#pragma unroll
            for (int reg = 0; reg < 4; reg++) {
                int co = (wid * 2 + c) * 16 + lhi * 4 + reg;
                int px = seg * 64 + ps * 16 + llo;
                out[((size_t)b * ldc + ch0 + co) * HW + h * Wd + px] = acc[c][ps][reg] + b_org[co];
            }
}

// ---- out = xa + lrelu(norm(dconv)) * (1 - attn) ----
__global__ void final_k(const float* __restrict__ rawAF, const float* __restrict__ xa,
                        const float* __restrict__ mu, const float* __restrict__ rsig,
                        float* __restrict__ outp) {
    size_t i4 = (size_t)blockIdx.x * BDIM + threadIdx.x;
    const size_t n4 = (size_t)BB * Cc * HW / 4;
    if (i4 >= n4) return;
    int plane = (int)(i4 / (HW / 4));
    int w4 = (int)(i4 % (HW / 4));
    int b = plane >> 7, c = plane & 127;
    const float4 a = *(const float4*)(rawAF + ((size_t)b * 256 + c) * HW + w4 * 4);
    float4 d = *(const float4*)(rawAF + ((size_t)b * 256 + 128 + c) * HW + w4 * 4);
    float4 xv = *(const float4*)(xa + (size_t)plane * HW + w4 * 4);
    float m = mu[plane], rs = rsig[plane];
    float4 o;
    float v;
    v = (d.x - m) * rs; v = v > 0.f ? v : 0.2f * v; o.x = xv.x + v * (1.f - a.x);
    v = (d.y - m) * rs; v = v > 0.f ? v : 0.2f * v; o.y = xv.y + v * (1.f - a.y);
    v = (d.z - m) * rs; v = v > 0.f ? v : 0.2f * v; o.z = xv.z + v * (1.f - a.z);
    v = (d.w - m) * rs; v = v > 0.f ? v : 0.2f * v; o.w = xv.w + v * (1.f - a.w);
    *(float4*)(outp + (size_t)plane * HW + w4 * 4) = o;
}

extern "C" void kernel_launch(void* const* d_in, const int* in_sizes, int n_in,
                              void* d_out, int out_size, void* d_ws, size_t ws_size,
                              hipStream_t stream) {
    const float* x      = (const float*)d_in[0];
    const float* w_attn = (const float*)d_in[1];
    const float* b_attn = (const float*)d_in[2];
    const float* w_feat = (const float*)d_in[3];
    const float* b_feat = (const float*)d_in[4];
    const float* w_org  = (const float*)d_in[5];
    const float* b_org  = (const float*)d_in[6];
    const float* w_off  = (const float*)d_in[7];
    const float* b_off  = (const float*)d_in[8];
    const float* w_mask = (const float*)d_in[9];
    const float* b_mask = (const float*)d_in[10];
    float* out = (float*)d_out;
    (void)in_sizes; (void)n_in; (void)out_size; (void)ws_size;

    float* ws = (float*)d_ws;
    size_t o = 0;
    float* rawAF = ws + o; o += (size_t)BB * 256 * HW;  // ch0-127: attn(sig); ch128-255: featRaw -> dconv
    float* xa    = ws + o; o += (size_t)BB * Cc * HW;
    float* offm  = ws + o; o += (size_t)BB * 32 * HW;
    unsigned short* wpkAF = (unsigned short*)(ws + o); o += 16 * 18432 / 2;
    unsigned short* wpkO  = (unsigned short*)(ws + o); o += 8 * 18432 / 2;
    unsigned short* wpkOM = (unsigned short*)(ws + o); o += 2 * 18432 / 2;
    float* bOM = ws + o; o += 32;
    float* mu1 = ws + o; o += 512;
    float* rs1 = ws + o; o += 512;
    float* mu2 = ws + o; o += 512;
    float* rs2 = ws + o; o += 512;

    // weight repacks
    repack_conv_k<<<(8 * 18432 + BDIM - 1) / BDIM, BDIM, 0, stream>>>(w_attn, wpkAF, 8, 128);
    repack_conv_k<<<(8 * 18432 + BDIM - 1) / BDIM, BDIM, 0, stream>>>(w_feat, wpkAF + 8 * 18432, 8, 128);
    repack_conv_k<<<(8 * 18432 + BDIM - 1) / BDIM, BDIM, 0, stream>>>(w_org, wpkO, 8, 128);
    repack_om_k<<<(2 * 18432 + BDIM - 1) / BDIM, BDIM, 0, stream>>>(w_off, w_mask, wpkOM);
    pack_bom_k<<<1, 32, 0, stream>>>(b_off, b_mask, bOM);

    // fused attn+feat conv (256 couts): sigmoid on ch<128
    convmf_k<4, 2><<<dim3(4, Hh, BB), BDIM, 0, stream>>>(
        x, wpkAF, b_attn, b_feat, 128, 128, rawAF, 256, 0);

    inorm_stats_k<<<BB * Cc, BDIM, 0, stream>>>(rawAF, mu1, rs1, 256, 128);

    const int n4 = BB * Cc * HW / 4;
    xattned_k<<<(n4 + BDIM - 1) / BDIM, BDIM, 0, stream>>>(rawAF, mu1, rs1, xa);

    // off/mask conv (32 padded couts, raw)
    convmf_k<2, 1><<<dim3(1, Hh, BB), BDIM, 0, stream>>>(
        xa, wpkOM, bOM, bOM, 32, 0, offm, 32, 0);

    // deformable conv -> rawAF ch 128..255 (feat raw is dead now)
    deform_mfma_k<<<dim3(2, Hh, BB), BDIM, 0, stream>>>(
        xa, offm, wpkO, b_org, rawAF, 256, 128);

    inorm_stats_k<<<BB * Cc, BDIM, 0, stream>>>(rawAF, mu2, rs2, 256, 128);

    final_k<<<(n4 + BDIM - 1) / BDIM, BDIM, 0, stream>>>(rawAF, xa, mu2, rs2, out);
}